// Round 1
// 413.211 us; speedup vs baseline: 1.1242x; 1.1242x over previous
//
#include <hip/hip_runtime.h>
#include <cstdint>

#define B_    2
#define NQ_   768
#define NK_   768
#define DE_   256
#define DI_   256
#define DM_   32
#define FF_   128
#define DO_   64
#define NB_   4

typedef float    f32x4  __attribute__((ext_vector_type(4)));
typedef _Float16 half8  __attribute__((ext_vector_type(8)));
typedef _Float16 half2v __attribute__((ext_vector_type(2)));

// ---------------------------------------------------------------------------
// Per-node precompute, v2: 4 nodes per 256-thread block, weights staged in
// LDS (We, then Wi reusing the same 32KB buffer) so the 256-long dot loops
// run at LDS throughput instead of chained global-load latency.
// grid = (1536/NB + 1, 2); blockIdx.y = 0 -> q side, 1 -> k side.
// Extra x-block packs W1[64:128]/W2 into MFMA fragment order (fp16).
// ---------------------------------------------------------------------------
__global__ __launch_bounds__(256) void node_pre_all(
    const float* __restrict__ q_inv, const float* __restrict__ q_equi,
    const float* __restrict__ k_inv, const float* __restrict__ k_equi,
    const float* __restrict__ Wqi, const float* __restrict__ bqi,
    const float* __restrict__ Wki, const float* __restrict__ bki,
    const float* __restrict__ Wqe, const float* __restrict__ bqe,
    const float* __restrict__ Wke, const float* __restrict__ bke,
    const float* __restrict__ W1,  const float* __restrict__ b1,
    const float* __restrict__ W2,
    float* __restrict__ qe, float* __restrict__ qq, float* __restrict__ Aq,
    float* __restrict__ ke, float* __restrict__ kk, float* __restrict__ Bk,
    _Float16* __restrict__ pk)
{
  const int side = blockIdx.y;
  const int t = threadIdx.x;

  if (blockIdx.x == (B_*NQ_)/NB_) {          // ---- weight-pack blocks ----
    if (side == 0) {
      for (int i = t; i < 8192; i += 256) {
        const int j = i & 7, ln = (i>>3)&63, s = (i>>9)&1, nt = i>>10;
        const int row = 64 + s*32 + (ln>>4)*8 + j, col = nt*16 + (ln&15);
        pk[i] = (_Float16)W1[row*FF_ + col];
      }
    } else {
      for (int i = t; i < 8192; i += 256) {
        const int j = i & 7, ln = (i>>3)&63, s = (i>>9)&3, nt = i>>11;
        const int row = s*32 + (ln>>4)*8 + j, col = nt*16 + (ln&15);
        pk[8192 + i] = (_Float16)W2[row*DO_ + col];
      }
    }
    return;
  }

  const float* inv  = side ? k_inv  : q_inv;
  const float* equi = side ? k_equi : q_equi;
  const float* Wi   = side ? Wki : Wqi;
  const float* bi   = side ? bki : bqi;
  const float* We   = side ? Wke : Wqe;
  const float* be   = side ? bke : bqe;
  const int w1RowOff = side ? 32 : 0;
  const int addB1    = side ? 0 : 1;
  float* e_out  = side ? ke : qe;
  float* sq_out = side ? kk : qq;
  float* ab_out = side ? Bk : Aq;

  __shared__ __align__(16) float W_s[DE_*DM_];      // 32 KB (We, then Wi)
  __shared__ __align__(16) float eq_s[NB_*3*DE_];   // 12 KB
  __shared__ __align__(16) float inv_s[NB_*DI_];    // 4 KB
  __shared__ float e_s[NB_*96];
  __shared__ float qi_s[NB_*DM_];

  const int node0 = blockIdx.x * NB_;

  { const f32x4* g = (const f32x4*)(equi + (size_t)node0*3*DE_);
    f32x4* d = (f32x4*)eq_s;
    #pragma unroll
    for (int i = 0; i < 3; ++i) d[t + 256*i] = g[t + 256*i]; }
  { const f32x4* g = (const f32x4*)(inv + (size_t)node0*DI_);
    ((f32x4*)inv_s)[t] = g[t]; }
  { const f32x4* g = (const f32x4*)We;
    f32x4* d = (f32x4*)W_s;
    #pragma unroll
    for (int i = 0; i < 8; ++i) d[t + 256*i] = g[t + 256*i]; }
  __syncthreads();

  auto dotW = [&](const float* __restrict__ x, const int m) -> float {
    float a0 = 0.f, a1 = 0.f, a2 = 0.f, a3 = 0.f;
    #pragma unroll 16
    for (int d = 0; d < 256; d += 4) {
      a0 = fmaf(x[d+0], W_s[(d+0)*DM_ + m], a0);
      a1 = fmaf(x[d+1], W_s[(d+1)*DM_ + m], a1);
      a2 = fmaf(x[d+2], W_s[(d+2)*DM_ + m], a2);
      a3 = fmaf(x[d+3], W_s[(d+3)*DM_ + m], a3);
    }
    return (a0+a1)+(a2+a3);
  };

  // e-phase: 4 nodes x 3 c x 32 m = 384 outputs (256 + 128)
  { const int node = t>>6, c = (t>>5)&1, m = t&31;
    const float v = be[m] + dotW(eq_s + node*3*DE_ + c*DE_, m);
    e_s[node*96 + c*32 + m] = v;
    e_out[(size_t)(node0+node)*96 + c*32 + m] = v; }
  if (t < 128) {
    const int node = t>>5, m = t&31;
    const float v = be[m] + dotW(eq_s + node*3*DE_ + 2*DE_, m);
    e_s[node*96 + 64 + m] = v;
    e_out[(size_t)(node0+node)*96 + 64 + m] = v; }
  __syncthreads();

  // stage Wi over We; concurrently sq from e_s
  { const f32x4* g = (const f32x4*)Wi;
    f32x4* d = (f32x4*)W_s;
    #pragma unroll
    for (int i = 0; i < 8; ++i) d[t + 256*i] = g[t + 256*i]; }
  if (t < NB_*32) {
    const int node = t>>5, m = t&31;
    const float v0 = e_s[node*96+m], v1 = e_s[node*96+32+m], v2 = e_s[node*96+64+m];
    sq_out[(size_t)(node0+node)*32 + m] = v0*v0 + v1*v1 + v2*v2; }
  __syncthreads();

  if (t < NB_*32) {
    const int node = t>>5, m = t&31;
    qi_s[node*32 + m] = bi[m] + dotW(inv_s + node*DI_, m); }
  __syncthreads();

  // ab-phase: 4 nodes x 128 ff = 512 outputs
  #pragma unroll
  for (int oo = 0; oo < 2; ++oo) {
    const int o = t + oo*256;
    const int node = o>>7, f = o&127;
    float acc = addB1 ? b1[f] : 0.f;
    #pragma unroll
    for (int m = 0; m < DM_; ++m)
      acc = fmaf(qi_s[node*32 + m], W1[(w1RowOff+m)*FF_ + f], acc);
    ab_out[(size_t)(node0+node)*FF_ + f] = acc;
  }
}

// ---------------------------------------------------------------------------
// Main pair kernel v2: transposed GEMMs (swap MFMA operands; A/B fragment
// layouts are symmetric so the same pk packing serves as W^T A-fragments).
//   GEMM1: acc1 = W1^T-tile . feat^T  -> lane holds col=pair(n15), rows=f
//   h handoff: per-wave 16x64-half LDS chunk (2.25 KB/wave, no barrier)
//   GEMM2: acc2 = W2^T-tile . h^T     -> lane holds col=pair, rows=o
//   epilogue: direct f32x4 stores (o contiguous per lane) - no transpose LDS
// LDS 34.9 KB, VGPR ~110 -> 4 blocks/CU (16 waves/CU vs previous 8).
// ---------------------------------------------------------------------------
__global__ __launch_bounds__(256, 4) void pair_main(
    const float* __restrict__ qe_g, const float* __restrict__ ke_g,
    const float* __restrict__ qq_g, const float* __restrict__ kk_g,
    const float* __restrict__ Aq_g, const float* __restrict__ Bk_g,
    const _Float16* __restrict__ pk, const float* __restrict__ b2,
    float* __restrict__ out)
{
  __shared__ __align__(16) float qe_s[8*100];
  __shared__ __align__(16) float ke_s[16*100];
  __shared__ __align__(16) float qq_s[8*36];
  __shared__ __align__(16) float kk_s[16*36];
  __shared__ __align__(16) float A_s[8*132];
  __shared__ __align__(16) float B_s[16*132];
  __shared__ __align__(16) _Float16 h_t[4][16*72];  // per-wave h^T chunk, row=pair (stride 72h=144B)

  const int tid = threadIdx.x;
  const int b  = blockIdx.z;
  const int q0 = blockIdx.y * 8;
  const int k0 = blockIdx.x * 16;

  // ---- staging: 1536 f32x4 chunks total = 6 per thread ----
  { const f32x4* p = (const f32x4*)(qe_g + ((size_t)b*NQ_ + q0)*96);
    if (tid < 192) ((f32x4*)qe_s)[(tid/24)*25 + tid%24] = p[tid]; }
  { const f32x4* p = (const f32x4*)(ke_g + ((size_t)b*NK_ + k0)*96);
    for (int i = tid; i < 384; i += 256) ((f32x4*)ke_s)[(i/24)*25 + i%24] = p[i]; }
  { const f32x4* p = (const f32x4*)(qq_g + ((size_t)b*NQ_ + q0)*32);
    if (tid < 64) ((f32x4*)qq_s)[(tid>>3)*9 + (tid&7)] = p[tid]; }
  { const f32x4* p = (const f32x4*)(kk_g + ((size_t)b*NK_ + k0)*32);
    if (tid < 128) ((f32x4*)kk_s)[(tid>>3)*9 + (tid&7)] = p[tid]; }
  { const f32x4* p = (const f32x4*)(Aq_g + ((size_t)b*NQ_ + q0)*128);
    ((f32x4*)A_s)[(tid>>5)*33 + (tid&31)] = p[tid]; }
  { const f32x4* p = (const f32x4*)(Bk_g + ((size_t)b*NK_ + k0)*128);
    for (int i = tid; i < 512; i += 256) ((f32x4*)B_s)[(i>>5)*33 + (i&31)] = p[i]; }
  __syncthreads();

  const int lane = tid & 63;
  const int w    = tid >> 6;       // wave owns qL = 2w, 2w+1
  const int n15  = lane & 15;
  const int quad = lane >> 4;
  const int mq   = quad * 8;

  const half8* pk1 = (const half8*)pk;
  const half8* pk2 = (const half8*)(pk + 8192);
  _Float16* hrow = &h_t[w][n15*72];

  half8 H[2][4];
  f32x4 acc2[2][4];
  #pragma unroll
  for (int t = 0; t < 2; ++t)
    #pragma unroll
    for (int nt = 0; nt < 4; ++nt)
      acc2[t][nt] = (f32x4){0.f,0.f,0.f,0.f};

  #pragma unroll
  for (int t = 0; t < 2; ++t) {
    const int qL = 2*w + t;

    // ---- feature fragments: feat[pair=n15][x=mq+j] ----
    f32x4 keF[6], kkF[2], qeF[6], qqF[2];
    #pragma unroll
    for (int c = 0; c < 3; ++c) {
      keF[c*2+0] = *(const f32x4*)&ke_s[n15*100 + c*32 + mq];
      keF[c*2+1] = *(const f32x4*)&ke_s[n15*100 + c*32 + mq + 4];
      qeF[c*2+0] = *(const f32x4*)&qe_s[qL*100 + c*32 + mq];
      qeF[c*2+1] = *(const f32x4*)&qe_s[qL*100 + c*32 + mq + 4];
    }
    kkF[0] = *(const f32x4*)&kk_s[n15*36 + mq];
    kkF[1] = *(const f32x4*)&kk_s[n15*36 + mq + 4];
    qqF[0] = *(const f32x4*)&qq_s[qL*36 + mq];
    qqF[1] = *(const f32x4*)&qq_s[qL*36 + mq + 4];

    half8 A0, A1;
    float dots[8];
    #pragma unroll
    for (int j = 0; j < 8; ++j) {
      const int h = j >> 2, e = j & 3;
      float d = qeF[0+h][e] * keF[0+h][e];
      d = fmaf(qeF[2+h][e], keF[2+h][e], d);
      d = fmaf(qeF[4+h][e], keF[4+h][e], d);
      dots[j] = d;
      A0[j] = (_Float16)d;
    }
    #pragma unroll
    for (int j = 0; j < 8; ++j) {
      const int h = j >> 2, e = j & 3;
      float v = qqF[h][e] + kkF[h][e] - 2.f*dots[j];
      v = fmaxf(v, 0.f);
      A1[j] = (_Float16)__builtin_sqrtf(v);
    }

    // ---- GEMM1 transposed: acc1[nt] = W1^T(16f x 32x) . feat^T(32x x 16p)
    f32x4 acc1[8];
    #pragma unroll
    for (int nt = 0; nt < 8; ++nt) acc1[nt] = (f32x4){0.f,0.f,0.f,0.f};
    {
      half8 B1s[8];
      #pragma unroll
      for (int nt = 0; nt < 8; ++nt) B1s[nt] = pk1[((nt*2 + 0)<<6) + lane];
      #pragma unroll
      for (int nt = 0; nt < 8; ++nt)
        acc1[nt] = __builtin_amdgcn_mfma_f32_16x16x32_f16(B1s[nt], A0, acc1[nt], 0, 0, 0);
      #pragma unroll
      for (int nt = 0; nt < 8; ++nt) B1s[nt] = pk1[((nt*2 + 1)<<6) + lane];
      #pragma unroll
      for (int nt = 0; nt < 8; ++nt)
        acc1[nt] = __builtin_amdgcn_mfma_f32_16x16x32_f16(B1s[nt], A1, acc1[nt], 0, 0, 0);
    }

    // ---- epilogue 1 in two 64-f chunks through the per-wave LDS tile ----
    // lane holds pre^T[f = nt*16 + quad*4 + r][pair = n15]
    #pragma unroll
    for (int ch = 0; ch < 2; ++ch) {
      #pragma unroll
      for (int ntl = 0; ntl < 4; ++ntl) {
        const int nt = ch*4 + ntl;
        const f32x4 Af = *(const f32x4*)&A_s[qL*132 + nt*16 + quad*4];
        const f32x4 Bf = *(const f32x4*)&B_s[n15*132 + nt*16 + quad*4];
        _Float16 hv[4];
        #pragma unroll
        for (int r = 0; r < 4; ++r) {
          const float x = acc1[nt][r] + Af[r] + Bf[r];
          const float e = __builtin_amdgcn_exp2f(-1.44269504f * x);
          hv[r] = (_Float16)(x * __builtin_amdgcn_rcpf(1.f + e));
        }
        half2v p0; p0[0] = hv[0]; p0[1] = hv[1];
        half2v p1; p1[0] = hv[2]; p1[1] = hv[3];
        *(half2v*)&hrow[ntl*16 + quad*4 + 0] = p0;   // row n15, in-wave transpose
        *(half2v*)&hrow[ntl*16 + quad*4 + 2] = p1;
      }
      // read back as B-fragment: h[p=n15][f = s*32 + mq + j]
      #pragma unroll
      for (int sl = 0; sl < 2; ++sl)
        H[t][ch*2 + sl] = *(const half8*)&hrow[sl*32 + mq];
    }
  }

  // ---- GEMM2 transposed: acc2 = W2^T(16o x 32f) . h^T(32f x 16p) ----
  #pragma unroll
  for (int s = 0; s < 4; ++s) {
    half8 B2s[4];
    #pragma unroll
    for (int nt = 0; nt < 4; ++nt) B2s[nt] = pk2[((nt*4 + s)<<6) + lane];
    #pragma unroll
    for (int t = 0; t < 2; ++t)
      #pragma unroll
      for (int nt = 0; nt < 4; ++nt)
        acc2[t][nt] = __builtin_amdgcn_mfma_f32_16x16x32_f16(B2s[nt], H[t][s], acc2[t][nt], 0, 0, 0);
  }

  // ---- epilogue 2: bias + direct stores (o = nt*16 + quad*4 + r per lane)
  f32x4 bias[4];
  #pragma unroll
  for (int nt = 0; nt < 4; ++nt) bias[nt] = *(const f32x4*)&b2[nt*16 + quad*4];
  const size_t outBase = (((size_t)b*NQ_ + q0)*NK_ + k0)*DO_;
  #pragma unroll
  for (int t = 0; t < 2; ++t) {
    const int qL = 2*w + t;
    float* orow = out + outBase + ((size_t)qL*NK_ + n15)*DO_;
    #pragma unroll
    for (int nt = 0; nt < 4; ++nt) {
      const f32x4 v = acc2[t][nt] + bias[nt];
      *(f32x4*)&orow[nt*16 + quad*4] = v;
    }
  }
}

extern "C" void kernel_launch(void* const* d_in, const int* in_sizes, int n_in,
                              void* d_out, int out_size, void* d_ws, size_t ws_size,
                              hipStream_t stream) {
  const float* q_equi = (const float*)d_in[0];
  const float* q_inv  = (const float*)d_in[1];
  const float* k_equi = (const float*)d_in[2];
  const float* k_inv  = (const float*)d_in[3];
  const float* Wqi = (const float*)d_in[4];
  const float* bqi = (const float*)d_in[5];
  const float* Wki = (const float*)d_in[6];
  const float* bki = (const float*)d_in[7];
  const float* Wqe = (const float*)d_in[8];
  const float* bqe = (const float*)d_in[9];
  const float* Wke = (const float*)d_in[10];
  const float* bke = (const float*)d_in[11];
  const float* W1  = (const float*)d_in[12];
  const float* b1  = (const float*)d_in[13];
  const float* W2  = (const float*)d_in[14];
  const float* b2  = (const float*)d_in[15];

  float* ws = (float*)d_ws;
  float* qe = ws;                           // [B*NQ][96]
  float* ke = qe + (size_t)B_*NQ_*96;       // [B*NK][96]
  float* qq = ke + (size_t)B_*NK_*96;       // [B*NQ][32]
  float* kk = qq + (size_t)B_*NQ_*32;       // [B*NK][32]
  float* Aq = kk + (size_t)B_*NK_*32;       // [B*NQ][128]
  float* Bk = Aq + (size_t)B_*NQ_*128;      // [B*NK][128]
  _Float16* pk = (_Float16*)(Bk + (size_t)B_*NK_*128);  // 16384 fp16

  dim3 ngrid(B_*NQ_/NB_ + 1, 2);
  node_pre_all<<<ngrid, 256, 0, stream>>>(
      q_inv, q_equi, k_inv, k_equi, Wqi, bqi, Wki, bki, Wqe, bqe, Wke, bke,
      W1, b1, W2, qe, qq, Aq, ke, kk, Bk, pk);

  dim3 grid(NK_/16, NQ_/8, B_);
  pair_main<<<grid, 256, 0, stream>>>(qe, ke, qq, kk, Aq, Bk, pk, b2, (float*)d_out);
}